// Round 2
// baseline (7401.618 us; speedup 1.0000x reference)
//
#include <hip/hip_runtime.h>

#define D 256
#define BM 128
#define BN 128
#define BK 16
#define KBLK 64
#define EPW 8
#define WPB 4
#define EPB 32

// ---------------- zero helper (avoid hipMemsetAsync under graph capture) ----
__global__ __launch_bounds__(256) void k_zero(float* __restrict__ p, int n) {
  int i = blockIdx.x * 256 + threadIdx.x;
  if (i < n) p[i] = 0.0f;
}

// ---------------- per-(relation,node) in-edge counts ----------------
__global__ __launch_bounds__(256) void k_count(const int* __restrict__ dst,
    const int* __restrict__ et, float* __restrict__ cnt, int E, int N) {
  int e = blockIdx.x * 256 + threadIdx.x;
  if (e >= E) return;
  atomicAdd(cnt + (size_t)et[e] * N + dst[e], 1.0f);
}

__global__ __launch_bounds__(256) void k_invcnt(float* __restrict__ cnt, int n) {
  int i = blockIdx.x * 256 + threadIdx.x;
  if (i >= n) return;
  cnt[i] = 1.0f / fmaxf(cnt[i], 1.0f);
}

// ---------------- bucket edges by relation (3 relations) ----------------
// meta[0..2] = cursors, meta[3..6] = relation start offsets
__global__ __launch_bounds__(256) void k_hist(const int* __restrict__ et,
    int* __restrict__ meta, int E) {
  int e = blockIdx.x * 256 + threadIdx.x;
  if (e >= E) return;
  atomicAdd(&meta[et[e]], 1);
}

__global__ void k_prefix(int* __restrict__ meta, int E) {
  if (threadIdx.x == 0 && blockIdx.x == 0) {
    int c0 = meta[0], c1 = meta[1];
    meta[3] = 0; meta[4] = c0; meta[5] = c0 + c1; meta[6] = E;
    meta[0] = 0; meta[1] = c0; meta[2] = c0 + c1;  // placement cursors
  }
}

__global__ __launch_bounds__(256) void k_place(const int* __restrict__ et,
    int* __restrict__ meta, int* __restrict__ es, int E) {
  int e = blockIdx.x * 256 + threadIdx.x;
  if (e >= E) return;
  int pos = atomicAdd(&meta[et[e]], 1);
  es[pos] = e;
}

// ---------------- fp32 GEMM: C[M,256] = A[gidx[M],256] @ B[256,256] (+bias) -
__global__ __launch_bounds__(256, 2) void k_gemm(const float* __restrict__ A,
    const int* __restrict__ gidx, const float* __restrict__ B,
    const float* __restrict__ bias, float* __restrict__ C, int M) {
  __shared__ float As[BK][BM + 4];
  __shared__ float Bs[BK][BN + 4];
  const int tid = threadIdx.x;
  const int row0 = blockIdx.x * BM;
  const int col0 = blockIdx.y * BN;
  const int tx = tid & 15;
  const int ty = tid >> 4;
  const int la_row = tid >> 1;
  const int la_k = (tid & 1) * 8;
  const int lb_k = tid >> 4;
  const int lb_col = (tid & 15) * 8;

  float acc[8][8];
#pragma unroll
  for (int i = 0; i < 8; i++)
#pragma unroll
    for (int j = 0; j < 8; j++) acc[i][j] = 0.0f;

  int ar = row0 + la_row;
  size_t arow = 0;
  if (ar < M) arow = (size_t)(gidx ? gidx[ar] : ar);

  for (int kt = 0; kt < D; kt += BK) {
    float4 a0, a1;
    if (ar < M) {
      const float* ap = A + arow * D + kt + la_k;
      a0 = *(const float4*)ap;
      a1 = *(const float4*)(ap + 4);
    } else {
      a0 = make_float4(0.f, 0.f, 0.f, 0.f);
      a1 = a0;
    }
    const float* bp = B + (kt + lb_k) * D + col0 + lb_col;
    float4 b0 = *(const float4*)bp;
    float4 b1 = *(const float4*)(bp + 4);

    __syncthreads();
    As[la_k + 0][la_row] = a0.x;
    As[la_k + 1][la_row] = a0.y;
    As[la_k + 2][la_row] = a0.z;
    As[la_k + 3][la_row] = a0.w;
    As[la_k + 4][la_row] = a1.x;
    As[la_k + 5][la_row] = a1.y;
    As[la_k + 6][la_row] = a1.z;
    As[la_k + 7][la_row] = a1.w;
    *(float4*)&Bs[lb_k][lb_col] = b0;
    *(float4*)&Bs[lb_k][lb_col + 4] = b1;
    __syncthreads();

#pragma unroll
    for (int k = 0; k < BK; k++) {
      float4 a01 = *(float4*)&As[k][ty * 8];
      float4 a23 = *(float4*)&As[k][ty * 8 + 4];
      float4 b01 = *(float4*)&Bs[k][tx * 8];
      float4 b23 = *(float4*)&Bs[k][tx * 8 + 4];
      float av[8] = {a01.x, a01.y, a01.z, a01.w, a23.x, a23.y, a23.z, a23.w};
      float bv[8] = {b01.x, b01.y, b01.z, b01.w, b23.x, b23.y, b23.z, b23.w};
#pragma unroll
      for (int i = 0; i < 8; i++)
#pragma unroll
        for (int j = 0; j < 8; j++) acc[i][j] = fmaf(av[i], bv[j], acc[i][j]);
    }
  }

  float bb[8];
#pragma unroll
  for (int j = 0; j < 8; j++)
    bb[j] = bias ? bias[col0 + tx * 8 + j] : 0.0f;

  const int crow = row0 + ty * 8;
#pragma unroll
  for (int i = 0; i < 8; i++) {
    int r = crow + i;
    if (r >= M) break;
    float* cp = C + (size_t)r * D + col0 + tx * 8;
    float4 v0, v1;
    v0.x = acc[i][0] + bb[0]; v0.y = acc[i][1] + bb[1];
    v0.z = acc[i][2] + bb[2]; v0.w = acc[i][3] + bb[3];
    v1.x = acc[i][4] + bb[4]; v1.y = acc[i][5] + bb[5];
    v1.z = acc[i][6] + bb[6]; v1.w = acc[i][7] + bb[7];
    *(float4*)cp = v0;
    *(float4*)(cp + 4) = v1;
  }
}

// ---------------- fused edge matvec: z[dst] += invc[dst]*(h[src] @ W_rel) ---
// edges pre-sorted by relation in es[]; one launch per relation.
// Block = 256 thr = 4 waves; 8 edges/wave; W staged in LDS 64-row blocks.
__global__ __launch_bounds__(256) void k_matvec(
    const float* __restrict__ h, const int* __restrict__ gidx,
    const float* __restrict__ W, const float* __restrict__ invc,
    const int* __restrict__ src, const int* __restrict__ dst,
    const int* __restrict__ es, const int* __restrict__ rstart,
    float* __restrict__ z, int rel) {
  __shared__ __align__(16) float Wb[KBLK * D];        // 64 KB
  __shared__ __align__(16) float Hs[WPB * EPW * KBLK]; // 8 KB
  const int lo = rstart[rel], hi = rstart[rel + 1];
  const int base = lo + blockIdx.x * EPB;
  if (base >= hi) return;  // block-uniform exit, before any barrier
  const int tid = threadIdx.x;
  const int wave = tid >> 6, lane = tid & 63;

  const float* hrow[EPW];
  int edst[EPW];
  bool valid[EPW];
#pragma unroll
  for (int t = 0; t < EPW; t++) {
    int p = base + wave * EPW + t;
    valid[t] = (p < hi);
    int e = es[valid[t] ? p : lo];
    int s = src[e];
    hrow[t] = h + (size_t)(gidx ? gidx[s] : s) * D;
    edst[t] = dst[e];
  }

  float acc[EPW][4];
#pragma unroll
  for (int t = 0; t < EPW; t++)
#pragma unroll
    for (int j = 0; j < 4; j++) acc[t][j] = 0.0f;

  for (int kb = 0; kb < D; kb += KBLK) {
    __syncthreads();  // previous iteration's reads done before overwrite
    const float* wp = W + (size_t)kb * D;
#pragma unroll
    for (int i = 0; i < 16; i++) {
      int idx = i * 1024 + tid * 4;  // 0..16383, coalesced float4
      *(float4*)&Wb[idx] = *(const float4*)(wp + idx);
    }
#pragma unroll
    for (int t = 0; t < EPW; t++)
      Hs[(wave * EPW + t) * KBLK + lane] = hrow[t][kb + lane];
    __syncthreads();

    for (int k4 = 0; k4 < KBLK; k4 += 4) {
      float4 w0 = *(float4*)&Wb[(k4 + 0) * D + lane * 4];
      float4 w1 = *(float4*)&Wb[(k4 + 1) * D + lane * 4];
      float4 w2 = *(float4*)&Wb[(k4 + 2) * D + lane * 4];
      float4 w3 = *(float4*)&Wb[(k4 + 3) * D + lane * 4];
#pragma unroll
      for (int t = 0; t < EPW; t++) {
        float4 hv = *(float4*)&Hs[(wave * EPW + t) * KBLK + k4];  // broadcast
        acc[t][0] = fmaf(hv.x, w0.x, acc[t][0]);
        acc[t][1] = fmaf(hv.x, w0.y, acc[t][1]);
        acc[t][2] = fmaf(hv.x, w0.z, acc[t][2]);
        acc[t][3] = fmaf(hv.x, w0.w, acc[t][3]);
        acc[t][0] = fmaf(hv.y, w1.x, acc[t][0]);
        acc[t][1] = fmaf(hv.y, w1.y, acc[t][1]);
        acc[t][2] = fmaf(hv.y, w1.z, acc[t][2]);
        acc[t][3] = fmaf(hv.y, w1.w, acc[t][3]);
        acc[t][0] = fmaf(hv.z, w2.x, acc[t][0]);
        acc[t][1] = fmaf(hv.z, w2.y, acc[t][1]);
        acc[t][2] = fmaf(hv.z, w2.z, acc[t][2]);
        acc[t][3] = fmaf(hv.z, w2.w, acc[t][3]);
        acc[t][0] = fmaf(hv.w, w3.x, acc[t][0]);
        acc[t][1] = fmaf(hv.w, w3.y, acc[t][1]);
        acc[t][2] = fmaf(hv.w, w3.z, acc[t][2]);
        acc[t][3] = fmaf(hv.w, w3.w, acc[t][3]);
      }
    }
  }

#pragma unroll
  for (int t = 0; t < EPW; t++) {
    if (!valid[t]) continue;
    float wgt = invc[edst[t]];
    float* zp = z + (size_t)edst[t] * D + lane * 4;
    atomicAdd(zp + 0, acc[t][0] * wgt);
    atomicAdd(zp + 1, acc[t][1] * wgt);
    atomicAdd(zp + 2, acc[t][2] * wgt);
    atomicAdd(zp + 3, acc[t][3] * wgt);
  }
}

// ---------------- in-place ReLU ----------------
__global__ __launch_bounds__(256) void k_relu(float* __restrict__ h, int n4) {
  int i = blockIdx.x * 256 + threadIdx.x;
  if (i >= n4) return;
  float4* p = (float4*)h + i;
  float4 v = *p;
  v.x = fmaxf(v.x, 0.f); v.y = fmaxf(v.y, 0.f);
  v.z = fmaxf(v.z, 0.f); v.w = fmaxf(v.w, 0.f);
  *p = v;
}

// ---------------- graph mean-pool accumulation ----------------
__global__ __launch_bounds__(256) void k_pool(const float* __restrict__ h,
    const int* __restrict__ batch, float* __restrict__ gsum,
    float* __restrict__ gcnt, int N) {
  int i = blockIdx.x * 4 + (threadIdx.x >> 6);
  if (i >= N) return;
  int lane = threadIdx.x & 63;
  int g = batch[i];
  float4 v = *(const float4*)(h + (size_t)i * D + lane * 4);
  float* p = gsum + (size_t)g * D + lane * 4;
  atomicAdd(p + 0, v.x);
  atomicAdd(p + 1, v.y);
  atomicAdd(p + 2, v.z);
  atomicAdd(p + 3, v.w);
  if (lane == 0) atomicAdd(gcnt + g, 1.0f);
}

// ---------------- head ----------------
__global__ __launch_bounds__(256) void k_final(const float* __restrict__ gsum,
    const float* __restrict__ gcnt, const float* __restrict__ linW,
    const float* __restrict__ linb, float* __restrict__ out, int G) {
  int g = blockIdx.x * 4 + (threadIdx.x >> 6);
  if (g >= G) return;
  int lane = threadIdx.x & 63;
  float inv = 1.0f / fmaxf(gcnt[g], 1.0f);
  float4 v = *(const float4*)(gsum + (size_t)g * D + lane * 4);
  float vv[4] = {v.x, v.y, v.z, v.w};
  float a0 = 0.f, a1 = 0.f, a2 = 0.f, a3 = 0.f;
#pragma unroll
  for (int j = 0; j < 4; j++) {
    float4 w = *(const float4*)(linW + (lane * 4 + j) * 4);
    float hv = vv[j] * inv;
    a0 = fmaf(hv, w.x, a0);
    a1 = fmaf(hv, w.y, a1);
    a2 = fmaf(hv, w.z, a2);
    a3 = fmaf(hv, w.w, a3);
  }
  for (int off = 32; off > 0; off >>= 1) {
    a0 += __shfl_down(a0, off, 64);
    a1 += __shfl_down(a1, off, 64);
    a2 += __shfl_down(a2, off, 64);
    a3 += __shfl_down(a3, off, 64);
  }
  if (lane == 0) {
    out[g * 4 + 0] = a0 + linb[0];
    out[g * 4 + 1] = a1 + linb[1];
    out[g * 4 + 2] = a2 + linb[2];
    out[g * 4 + 3] = a3 + linb[3];
  }
}

extern "C" void kernel_launch(void* const* d_in, const int* in_sizes, int n_in,
                              void* d_out, int out_size, void* d_ws, size_t ws_size,
                              hipStream_t stream) {
  const int*   x     = (const int*)d_in[0];
  const int*   ei    = (const int*)d_in[1];
  const int*   et    = (const int*)d_in[2];
  const int*   batch = (const int*)d_in[3];
  const float* table = (const float*)d_in[5];
  const float* W1    = (const float*)d_in[6];
  const float* root1 = (const float*)d_in[7];
  const float* b1    = (const float*)d_in[8];
  const float* W2    = (const float*)d_in[9];
  const float* root2 = (const float*)d_in[10];
  const float* b2    = (const float*)d_in[11];
  const float* linW  = (const float*)d_in[12];
  const float* linb  = (const float*)d_in[13];
  float* out = (float*)d_out;

  const int N = in_sizes[0];
  const int E = in_sizes[2];
  const int G = out_size / 4;
  const int R = in_sizes[6] / (D * D);  // 3
  const int* src = ei;
  const int* dst = ei + E;

  // ws layout (≈208 MB): bufA(N*D) | bufB(N*D) | cnt(3N) | gsum(G*D) |
  //                      gcnt(G) | meta(8 int) | es(E int)
  float* ws = (float*)d_ws;
  size_t nh = (size_t)N * D;
  float* bufA = ws;
  float* bufB = bufA + nh;
  float* cnt  = bufB + nh;
  float* gsum = cnt + (size_t)R * N;
  float* gcnt = gsum + (size_t)G * D;
  int*   meta = (int*)(gcnt + G);
  int*   es   = meta + 8;

  // zero cnt | gsum | gcnt | meta in one shot (int 0 == float 0.0 bits)
  int nz = R * N + G * D + G + 8;
  k_zero<<<(nz + 255) / 256, 256, 0, stream>>>(cnt, nz);

  k_count<<<(E + 255) / 256, 256, 0, stream>>>(dst, et, cnt, E, N);
  k_invcnt<<<(R * N + 255) / 256, 256, 0, stream>>>(cnt, R * N);
  k_hist<<<(E + 255) / 256, 256, 0, stream>>>(et, meta, E);
  k_prefix<<<1, 64, 0, stream>>>(meta, E);
  k_place<<<(E + 255) / 256, 256, 0, stream>>>(et, meta, es, E);

  dim3 gg((N + BM - 1) / BM, D / BN);
  int mvg = (E + EPB - 1) / EPB;

  // ---- layer 1 (input = table gathered via x) ----
  k_gemm<<<gg, 256, 0, stream>>>(table, x, root1, b1, bufA, N);
  for (int r = 0; r < R; r++)
    k_matvec<<<mvg, 256, 0, stream>>>(table, x, W1 + (size_t)r * D * D,
        cnt + (size_t)r * N, src, dst, es, meta + 3, bufA, r);
  k_relu<<<((N * D / 4) + 255) / 256, 256, 0, stream>>>(bufA, N * D / 4);

  // ---- layer 2 ----
  k_gemm<<<gg, 256, 0, stream>>>(bufA, nullptr, root2, b2, bufB, N);
  for (int r = 0; r < R; r++)
    k_matvec<<<mvg, 256, 0, stream>>>(bufA, nullptr, W2 + (size_t)r * D * D,
        cnt + (size_t)r * N, src, dst, es, meta + 3, bufB, r);
  k_relu<<<((N * D / 4) + 255) / 256, 256, 0, stream>>>(bufB, N * D / 4);

  // ---- pool + head ----
  k_pool<<<(N + 3) / 4, 256, 0, stream>>>(bufB, batch, gsum, gcnt, N);
  k_final<<<(G + 3) / 4, 256, 0, stream>>>(gsum, gcnt, linW, linb, out, G);
}

// Round 3
// 2990.224 us; speedup vs baseline: 2.4753x; 2.4753x over previous
//
#include <hip/hip_runtime.h>

#define D 256
#define BM 128
#define BN 128
#define BK 16
#define KBLK 64
#define EPW 8
#define WPB 4
#define EPB 32

// ---------------- zero helper (avoid hipMemsetAsync under graph capture) ----
__global__ __launch_bounds__(256) void k_zero(float* __restrict__ p, int n) {
  int i = blockIdx.x * 256 + threadIdx.x;
  if (i < n) p[i] = 0.0f;
}

// ---------------- per-(relation,node) in-edge counts ----------------
__global__ __launch_bounds__(256) void k_count(const int* __restrict__ dst,
    const int* __restrict__ et, float* __restrict__ cnt, int E, int N) {
  int e = blockIdx.x * 256 + threadIdx.x;
  if (e >= E) return;
  atomicAdd(cnt + (size_t)et[e] * N + dst[e], 1.0f);
}

__global__ __launch_bounds__(256) void k_invcnt(float* __restrict__ cnt, int n) {
  int i = blockIdx.x * 256 + threadIdx.x;
  if (i >= n) return;
  cnt[i] = 1.0f / fmaxf(cnt[i], 1.0f);
}

// ---------------- bucket edges by relation (3 relations) ----------------
// meta[0..2] = totals then cursors, meta[3..6] = relation start offsets
// Block-aggregated: 3 global atomics per block instead of 256.
__global__ __launch_bounds__(256) void k_hist(const int* __restrict__ et,
    int* __restrict__ meta, int E) {
  __shared__ int lcnt[3];
  int tid = threadIdx.x;
  if (tid < 3) lcnt[tid] = 0;
  __syncthreads();
  int e = blockIdx.x * 256 + tid;
  if (e < E) atomicAdd(&lcnt[et[e]], 1);
  __syncthreads();
  if (tid < 3 && lcnt[tid] > 0) atomicAdd(&meta[tid], lcnt[tid]);
}

__global__ void k_prefix(int* __restrict__ meta, int E) {
  if (threadIdx.x == 0 && blockIdx.x == 0) {
    int c0 = meta[0], c1 = meta[1];
    meta[3] = 0; meta[4] = c0; meta[5] = c0 + c1; meta[6] = E;
    meta[0] = 0; meta[1] = c0; meta[2] = c0 + c1;  // placement cursors
  }
}

__global__ __launch_bounds__(256) void k_place(const int* __restrict__ et,
    int* __restrict__ meta, int* __restrict__ es, int E) {
  __shared__ int lcnt[3];
  __shared__ int lbase[3];
  int tid = threadIdx.x;
  if (tid < 3) lcnt[tid] = 0;
  __syncthreads();
  int e = blockIdx.x * 256 + tid;
  int r = 0, my = 0;
  if (e < E) {
    r = et[e];
    my = atomicAdd(&lcnt[r], 1);   // LDS atomic: cheap, block-local rank
  }
  __syncthreads();
  if (tid < 3) lbase[tid] = lcnt[tid] ? atomicAdd(&meta[tid], lcnt[tid]) : 0;
  __syncthreads();
  if (e < E) es[lbase[r] + my] = e;
}

// ---------------- graph boundaries from sorted batch ----------------
// gstart[g] = first node index with batch[i] >= g; gstart[G] = N
__global__ __launch_bounds__(256) void k_bounds(const int* __restrict__ batch,
    int* __restrict__ gstart, int N, int G) {
  int i = blockIdx.x * 256 + threadIdx.x;
  if (i >= N) return;
  int b = batch[i];
  if (i == 0) {
    for (int g = 0; g <= b; g++) gstart[g] = 0;
  } else {
    int pb = batch[i - 1];
    for (int g = pb + 1; g <= b; g++) gstart[g] = i;
  }
  if (i == N - 1) {
    for (int g = b + 1; g <= G; g++) gstart[g] = N;
  }
}

// ---------------- fp32 GEMM: C[M,256] = A[gidx[M],256] @ B[256,256] (+bias) -
__global__ __launch_bounds__(256, 2) void k_gemm(const float* __restrict__ A,
    const int* __restrict__ gidx, const float* __restrict__ B,
    const float* __restrict__ bias, float* __restrict__ C, int M) {
  __shared__ float As[BK][BM + 4];
  __shared__ float Bs[BK][BN + 4];
  const int tid = threadIdx.x;
  const int row0 = blockIdx.x * BM;
  const int col0 = blockIdx.y * BN;
  const int tx = tid & 15;
  const int ty = tid >> 4;
  const int la_row = tid >> 1;
  const int la_k = (tid & 1) * 8;
  const int lb_k = tid >> 4;
  const int lb_col = (tid & 15) * 8;

  float acc[8][8];
#pragma unroll
  for (int i = 0; i < 8; i++)
#pragma unroll
    for (int j = 0; j < 8; j++) acc[i][j] = 0.0f;

  int ar = row0 + la_row;
  size_t arow = 0;
  if (ar < M) arow = (size_t)(gidx ? gidx[ar] : ar);

  for (int kt = 0; kt < D; kt += BK) {
    float4 a0, a1;
    if (ar < M) {
      const float* ap = A + arow * D + kt + la_k;
      a0 = *(const float4*)ap;
      a1 = *(const float4*)(ap + 4);
    } else {
      a0 = make_float4(0.f, 0.f, 0.f, 0.f);
      a1 = a0;
    }
    const float* bp = B + (kt + lb_k) * D + col0 + lb_col;
    float4 b0 = *(const float4*)bp;
    float4 b1 = *(const float4*)(bp + 4);

    __syncthreads();
    As[la_k + 0][la_row] = a0.x;
    As[la_k + 1][la_row] = a0.y;
    As[la_k + 2][la_row] = a0.z;
    As[la_k + 3][la_row] = a0.w;
    As[la_k + 4][la_row] = a1.x;
    As[la_k + 5][la_row] = a1.y;
    As[la_k + 6][la_row] = a1.z;
    As[la_k + 7][la_row] = a1.w;
    *(float4*)&Bs[lb_k][lb_col] = b0;
    *(float4*)&Bs[lb_k][lb_col + 4] = b1;
    __syncthreads();

#pragma unroll
    for (int k = 0; k < BK; k++) {
      float4 a01 = *(float4*)&As[k][ty * 8];
      float4 a23 = *(float4*)&As[k][ty * 8 + 4];
      float4 b01 = *(float4*)&Bs[k][tx * 8];
      float4 b23 = *(float4*)&Bs[k][tx * 8 + 4];
      float av[8] = {a01.x, a01.y, a01.z, a01.w, a23.x, a23.y, a23.z, a23.w};
      float bv[8] = {b01.x, b01.y, b01.z, b01.w, b23.x, b23.y, b23.z, b23.w};
#pragma unroll
      for (int i = 0; i < 8; i++)
#pragma unroll
        for (int j = 0; j < 8; j++) acc[i][j] = fmaf(av[i], bv[j], acc[i][j]);
    }
  }

  float bb[8];
#pragma unroll
  for (int j = 0; j < 8; j++)
    bb[j] = bias ? bias[col0 + tx * 8 + j] : 0.0f;

  const int crow = row0 + ty * 8;
#pragma unroll
  for (int i = 0; i < 8; i++) {
    int r = crow + i;
    if (r >= M) break;
    float* cp = C + (size_t)r * D + col0 + tx * 8;
    float4 v0, v1;
    v0.x = acc[i][0] + bb[0]; v0.y = acc[i][1] + bb[1];
    v0.z = acc[i][2] + bb[2]; v0.w = acc[i][3] + bb[3];
    v1.x = acc[i][4] + bb[4]; v1.y = acc[i][5] + bb[5];
    v1.z = acc[i][6] + bb[6]; v1.w = acc[i][7] + bb[7];
    *(float4*)cp = v0;
    *(float4*)(cp + 4) = v1;
  }
}

// ---------------- fused edge matvec: z[dst] += invc[dst]*(h[src] @ W_rel) ---
__global__ __launch_bounds__(256) void k_matvec(
    const float* __restrict__ h, const int* __restrict__ gidx,
    const float* __restrict__ W, const float* __restrict__ invc,
    const int* __restrict__ src, const int* __restrict__ dst,
    const int* __restrict__ es, const int* __restrict__ rstart,
    float* __restrict__ z, int rel) {
  __shared__ __align__(16) float Wb[KBLK * D];        // 64 KB
  __shared__ __align__(16) float Hs[WPB * EPW * KBLK]; // 8 KB
  const int lo = rstart[rel], hi = rstart[rel + 1];
  const int base = lo + blockIdx.x * EPB;
  if (base >= hi) return;  // block-uniform exit, before any barrier
  const int tid = threadIdx.x;
  const int wave = tid >> 6, lane = tid & 63;

  const float* hrow[EPW];
  int edst[EPW];
  bool valid[EPW];
#pragma unroll
  for (int t = 0; t < EPW; t++) {
    int p = base + wave * EPW + t;
    valid[t] = (p < hi);
    int e = es[valid[t] ? p : lo];
    int s = src[e];
    hrow[t] = h + (size_t)(gidx ? gidx[s] : s) * D;
    edst[t] = dst[e];
  }

  float acc[EPW][4];
#pragma unroll
  for (int t = 0; t < EPW; t++)
#pragma unroll
    for (int j = 0; j < 4; j++) acc[t][j] = 0.0f;

  for (int kb = 0; kb < D; kb += KBLK) {
    __syncthreads();
    const float* wp = W + (size_t)kb * D;
#pragma unroll
    for (int i = 0; i < 16; i++) {
      int idx = i * 1024 + tid * 4;
      *(float4*)&Wb[idx] = *(const float4*)(wp + idx);
    }
#pragma unroll
    for (int t = 0; t < EPW; t++)
      Hs[(wave * EPW + t) * KBLK + lane] = hrow[t][kb + lane];
    __syncthreads();

    for (int k4 = 0; k4 < KBLK; k4 += 4) {
      float4 w0 = *(float4*)&Wb[(k4 + 0) * D + lane * 4];
      float4 w1 = *(float4*)&Wb[(k4 + 1) * D + lane * 4];
      float4 w2 = *(float4*)&Wb[(k4 + 2) * D + lane * 4];
      float4 w3 = *(float4*)&Wb[(k4 + 3) * D + lane * 4];
#pragma unroll
      for (int t = 0; t < EPW; t++) {
        float4 hv = *(float4*)&Hs[(wave * EPW + t) * KBLK + k4];
        acc[t][0] = fmaf(hv.x, w0.x, acc[t][0]);
        acc[t][1] = fmaf(hv.x, w0.y, acc[t][1]);
        acc[t][2] = fmaf(hv.x, w0.z, acc[t][2]);
        acc[t][3] = fmaf(hv.x, w0.w, acc[t][3]);
        acc[t][0] = fmaf(hv.y, w1.x, acc[t][0]);
        acc[t][1] = fmaf(hv.y, w1.y, acc[t][1]);
        acc[t][2] = fmaf(hv.y, w1.z, acc[t][2]);
        acc[t][3] = fmaf(hv.y, w1.w, acc[t][3]);
        acc[t][0] = fmaf(hv.z, w2.x, acc[t][0]);
        acc[t][1] = fmaf(hv.z, w2.y, acc[t][1]);
        acc[t][2] = fmaf(hv.z, w2.z, acc[t][2]);
        acc[t][3] = fmaf(hv.z, w2.w, acc[t][3]);
        acc[t][0] = fmaf(hv.w, w3.x, acc[t][0]);
        acc[t][1] = fmaf(hv.w, w3.y, acc[t][1]);
        acc[t][2] = fmaf(hv.w, w3.z, acc[t][2]);
        acc[t][3] = fmaf(hv.w, w3.w, acc[t][3]);
      }
    }
  }

#pragma unroll
  for (int t = 0; t < EPW; t++) {
    if (!valid[t]) continue;
    float wgt = invc[edst[t]];
    float* zp = z + (size_t)edst[t] * D + lane * 4;
    atomicAdd(zp + 0, acc[t][0] * wgt);
    atomicAdd(zp + 1, acc[t][1] * wgt);
    atomicAdd(zp + 2, acc[t][2] * wgt);
    atomicAdd(zp + 3, acc[t][3] * wgt);
  }
}

// ---------------- in-place ReLU ----------------
__global__ __launch_bounds__(256) void k_relu(float* __restrict__ h, int n4) {
  int i = blockIdx.x * 256 + threadIdx.x;
  if (i >= n4) return;
  float4* p = (float4*)h + i;
  float4 v = *p;
  v.x = fmaxf(v.x, 0.f); v.y = fmaxf(v.y, 0.f);
  v.z = fmaxf(v.z, 0.f); v.w = fmaxf(v.w, 0.f);
  *p = v;
}

// ---------------- graph mean-pool: one block per graph, no atomics ---------
__global__ __launch_bounds__(256) void k_pool(const float* __restrict__ h,
    const int* __restrict__ gstart, float* __restrict__ gmean, int G) {
  __shared__ float red[4][D];
  int g = blockIdx.x;
  int lo = gstart[g], hi = gstart[g + 1];
  int tid = threadIdx.x, wave = tid >> 6, lane = tid & 63;
  float4 a = make_float4(0.f, 0.f, 0.f, 0.f);
  for (int i = lo + wave; i < hi; i += 4) {
    float4 v = *(const float4*)(h + (size_t)i * D + lane * 4);
    a.x += v.x; a.y += v.y; a.z += v.z; a.w += v.w;
  }
  *(float4*)&red[wave][lane * 4] = a;
  __syncthreads();
  float s = red[0][tid] + red[1][tid] + red[2][tid] + red[3][tid];
  float inv = (hi > lo) ? 1.0f / (float)(hi - lo) : 0.0f;
  gmean[(size_t)g * D + tid] = s * inv;
}

// ---------------- head: out[g][:] = gmean[g] @ lin_W + lin_b ----------------
__global__ __launch_bounds__(256) void k_final(const float* __restrict__ gmean,
    const float* __restrict__ linW, const float* __restrict__ linb,
    float* __restrict__ out, int G) {
  int g = blockIdx.x * 4 + (threadIdx.x >> 6);
  if (g >= G) return;
  int lane = threadIdx.x & 63;
  float4 v = *(const float4*)(gmean + (size_t)g * D + lane * 4);
  float vv[4] = {v.x, v.y, v.z, v.w};
  float a0 = 0.f, a1 = 0.f, a2 = 0.f, a3 = 0.f;
#pragma unroll
  for (int j = 0; j < 4; j++) {
    float4 w = *(const float4*)(linW + (lane * 4 + j) * 4);
    a0 = fmaf(vv[j], w.x, a0);
    a1 = fmaf(vv[j], w.y, a1);
    a2 = fmaf(vv[j], w.z, a2);
    a3 = fmaf(vv[j], w.w, a3);
  }
  for (int off = 32; off > 0; off >>= 1) {
    a0 += __shfl_down(a0, off, 64);
    a1 += __shfl_down(a1, off, 64);
    a2 += __shfl_down(a2, off, 64);
    a3 += __shfl_down(a3, off, 64);
  }
  if (lane == 0) {
    out[g * 4 + 0] = a0 + linb[0];
    out[g * 4 + 1] = a1 + linb[1];
    out[g * 4 + 2] = a2 + linb[2];
    out[g * 4 + 3] = a3 + linb[3];
  }
}

extern "C" void kernel_launch(void* const* d_in, const int* in_sizes, int n_in,
                              void* d_out, int out_size, void* d_ws, size_t ws_size,
                              hipStream_t stream) {
  const int*   x     = (const int*)d_in[0];
  const int*   ei    = (const int*)d_in[1];
  const int*   et    = (const int*)d_in[2];
  const int*   batch = (const int*)d_in[3];
  const float* table = (const float*)d_in[5];
  const float* W1    = (const float*)d_in[6];
  const float* root1 = (const float*)d_in[7];
  const float* b1    = (const float*)d_in[8];
  const float* W2    = (const float*)d_in[9];
  const float* root2 = (const float*)d_in[10];
  const float* b2    = (const float*)d_in[11];
  const float* linW  = (const float*)d_in[12];
  const float* linb  = (const float*)d_in[13];
  float* out = (float*)d_out;

  const int N = in_sizes[0];
  const int E = in_sizes[2];
  const int G = out_size / 4;
  const int R = in_sizes[6] / (D * D);  // 3
  const int* src = ei;
  const int* dst = ei + E;

  // ws layout (≈208 MB): bufA(N*D) | bufB(N*D) | cnt(R*N) | gmean(G*D) |
  //                      gstart(G+1 int) | meta(8 int) | es(E int)
  float* ws = (float*)d_ws;
  size_t nh = (size_t)N * D;
  float* bufA  = ws;
  float* bufB  = bufA + nh;
  float* cnt   = bufB + nh;
  float* gmean = cnt + (size_t)R * N;
  int*   gstart = (int*)(gmean + (size_t)G * D);
  int*   meta  = gstart + (G + 1);
  int*   es    = meta + 8;

  // zero cnt (R*N floats) + skip gmean (fully written) ... zero meta too.
  k_zero<<<(R * N + 255) / 256, 256, 0, stream>>>(cnt, R * N);
  k_zero<<<1, 64, 0, stream>>>((float*)meta, 8);  // int 0 == float 0.0 bits

  k_count<<<(E + 255) / 256, 256, 0, stream>>>(dst, et, cnt, E, N);
  k_invcnt<<<(R * N + 255) / 256, 256, 0, stream>>>(cnt, R * N);
  k_hist<<<(E + 255) / 256, 256, 0, stream>>>(et, meta, E);
  k_prefix<<<1, 64, 0, stream>>>(meta, E);
  k_place<<<(E + 255) / 256, 256, 0, stream>>>(et, meta, es, E);
  k_bounds<<<(N + 255) / 256, 256, 0, stream>>>(batch, gstart, N, G);

  dim3 gg((N + BM - 1) / BM, D / BN);
  int mvg = (E + EPB - 1) / EPB;

  // ---- layer 1 (input = table gathered via x) ----
  k_gemm<<<gg, 256, 0, stream>>>(table, x, root1, b1, bufA, N);
  for (int r = 0; r < R; r++)
    k_matvec<<<mvg, 256, 0, stream>>>(table, x, W1 + (size_t)r * D * D,
        cnt + (size_t)r * N, src, dst, es, meta + 3, bufA, r);
  k_relu<<<((N * D / 4) + 255) / 256, 256, 0, stream>>>(bufA, N * D / 4);

  // ---- layer 2 ----
  k_gemm<<<gg, 256, 0, stream>>>(bufA, nullptr, root2, b2, bufB, N);
  for (int r = 0; r < R; r++)
    k_matvec<<<mvg, 256, 0, stream>>>(bufA, nullptr, W2 + (size_t)r * D * D,
        cnt + (size_t)r * N, src, dst, es, meta + 3, bufB, r);
  k_relu<<<((N * D / 4) + 255) / 256, 256, 0, stream>>>(bufB, N * D / 4);

  // ---- pool + head ----
  k_pool<<<G, 256, 0, stream>>>(bufB, gstart, gmean, G);
  k_final<<<(G + 3) / 4, 256, 0, stream>>>(gmean, linW, linb, out, G);
}

// Round 4
// 2023.480 us; speedup vs baseline: 3.6579x; 1.4778x over previous
//
#include <hip/hip_runtime.h>

#define D 256
#define BM 128
#define BN 128
#define BK 16
#define SB 1024   // scan elements per block

// ---------------- int zero ----------------
__global__ __launch_bounds__(256) void k_zero_i(int* __restrict__ p, int n) {
  int i = blockIdx.x * 256 + threadIdx.x;
  if (i < n) p[i] = 0;
}

// ---------------- per-(relation,node) in-edge counts (int) ----------------
__global__ __launch_bounds__(256) void k_count_i(const int* __restrict__ dst,
    const int* __restrict__ et, int* __restrict__ cnt, int E, int N) {
  int e = blockIdx.x * 256 + threadIdx.x;
  if (e >= E) return;
  atomicAdd(&cnt[et[e] * N + dst[e]], 1);  // ~Poisson(1) per cell: low contention
}

// ---------------- 3-kernel exclusive scan over n ints ----------------
__global__ __launch_bounds__(256) void k_scan1(const int* __restrict__ in,
    int* __restrict__ bsum, int n) {
  __shared__ int s[256];
  int base = blockIdx.x * SB, t = threadIdx.x;
  int a = 0;
#pragma unroll
  for (int j = 0; j < 4; j++) { int i = base + t * 4 + j; if (i < n) a += in[i]; }
  s[t] = a; __syncthreads();
  for (int o = 128; o > 0; o >>= 1) { if (t < o) s[t] += s[t + o]; __syncthreads(); }
  if (t == 0) bsum[blockIdx.x] = s[0];
}

__global__ void k_scan2(int* __restrict__ bsum, int nb, int* __restrict__ total_out) {
  if (threadIdx.x == 0 && blockIdx.x == 0) {
    int acc = 0;
    for (int i = 0; i < nb; i++) { int v = bsum[i]; bsum[i] = acc; acc += v; }
    *total_out = acc;   // off[3N] = E
  }
}

// writes exclusive scan into off[i] AND cur[i]
__global__ __launch_bounds__(256) void k_scan3(const int* __restrict__ in,
    const int* __restrict__ bsum, int* __restrict__ off, int* __restrict__ cur,
    int n) {
  __shared__ int s[256];
  int base = blockIdx.x * SB, t = threadIdx.x;
  int v[4]; int a = 0;
#pragma unroll
  for (int j = 0; j < 4; j++) {
    int i = base + t * 4 + j;
    v[j] = (i < n) ? in[i] : 0;
    a += v[j];
  }
  s[t] = a; __syncthreads();
  for (int o = 1; o < 256; o <<= 1) {
    int x_ = (t >= o) ? s[t - o] : 0;
    __syncthreads();
    s[t] += x_;
    __syncthreads();
  }
  int excl = (t > 0 ? s[t - 1] : 0) + bsum[blockIdx.x];
#pragma unroll
  for (int j = 0; j < 4; j++) {
    int i = base + t * 4 + j;
    if (i < n) { off[i] = excl; cur[i] = excl; excl += v[j]; }
  }
}

// ---------------- CSR placement: es[pos] = src node id ----------------
__global__ __launch_bounds__(256) void k_place2(const int* __restrict__ src,
    const int* __restrict__ dst, const int* __restrict__ et,
    int* __restrict__ cur, int* __restrict__ es, int E, int N) {
  int e = blockIdx.x * 256 + threadIdx.x;
  if (e >= E) return;
  int pos = atomicAdd(&cur[et[e] * N + dst[e]], 1);
  es[pos] = src[e];
}

// ---------------- graph boundaries from sorted batch ----------------
__global__ __launch_bounds__(256) void k_bounds(const int* __restrict__ batch,
    int* __restrict__ gstart, int N, int G) {
  int i = blockIdx.x * 256 + threadIdx.x;
  if (i >= N) return;
  int b = batch[i];
  if (i == 0) { for (int g = 0; g <= b; g++) gstart[g] = 0; }
  else { int pb = batch[i - 1]; for (int g = pb + 1; g <= b; g++) gstart[g] = i; }
  if (i == N - 1) { for (int g = b + 1; g <= G; g++) gstart[g] = N; }
}

// ---------------- fused layer GEMM, K=1024 (root | 3 gathered relations) ---
// C[i,:] = relu( Aroot[rowA(i),:]@root + b
//              + sum_r invc_r(i) * (sum_{e in CSR[r][i]} Hg[srcrow(e),:]) @ W_r )
// A-tile staging does the CSR gather-sum inline; no agg buffer, no atomics.
__global__ __launch_bounds__(256, 2) void k_lgemm(
    const float* __restrict__ Aroot, const int* __restrict__ gidx,
    const float* __restrict__ Hg, const int* __restrict__ gidxE,
    const int* __restrict__ es, const int* __restrict__ off,
    const float* __restrict__ root, const float* __restrict__ W,
    const float* __restrict__ bias, float* __restrict__ C, int M, int NN) {
  __shared__ float As[BK][BM + 4];
  __shared__ float Bs[BK][BN + 4];
  const int tid = threadIdx.x;
  const int row0 = blockIdx.x * BM, col0 = blockIdx.y * BN;
  const int tx = tid & 15, ty = tid >> 4;
  const int la_row = tid >> 1, la_k = (tid & 1) * 8;
  const int lb_k = tid >> 4, lb_col = (tid & 15) * 8;

  float acc[8][8];
#pragma unroll
  for (int i = 0; i < 8; i++)
#pragma unroll
    for (int j = 0; j < 8; j++) acc[i][j] = 0.0f;

  const int ar = row0 + la_row;
  const bool av = (ar < M);
  size_t rowA = 0;
  int lo[3] = {0, 0, 0}, hi[3] = {0, 0, 0};
  float inv[3] = {0.f, 0.f, 0.f};
  if (av) {
    rowA = (size_t)(gidx ? gidx[ar] : ar);
#pragma unroll
    for (int r = 0; r < 3; r++) {
      lo[r] = off[r * NN + ar];
      hi[r] = off[r * NN + ar + 1];
      int c = hi[r] - lo[r];
      inv[r] = 1.0f / (float)(c > 0 ? c : 1);
    }
  }

  for (int seg = 0; seg < 4; ++seg) {
    const float* Bbase = (seg == 0) ? root : (W + (size_t)(seg - 1) * D * D);
    for (int kk = 0; kk < D; kk += BK) {
      float a[8];
      if (seg == 0) {
        if (av) {
          const float* ap = Aroot + rowA * D + kk + la_k;
          float4 a0 = *(const float4*)ap;
          float4 a1 = *(const float4*)(ap + 4);
          a[0] = a0.x; a[1] = a0.y; a[2] = a0.z; a[3] = a0.w;
          a[4] = a1.x; a[5] = a1.y; a[6] = a1.z; a[7] = a1.w;
        } else {
#pragma unroll
          for (int j = 0; j < 8; j++) a[j] = 0.0f;
        }
      } else {
        int r = seg - 1;
        float4 s0 = make_float4(0.f, 0.f, 0.f, 0.f), s1 = s0;
        for (int p = lo[r]; p < hi[r]; ++p) {
          int s = es[p];
          if (gidxE) s = gidxE[s];
          const float* hp = Hg + (size_t)s * D + kk + la_k;
          float4 h0 = *(const float4*)hp;
          float4 h1 = *(const float4*)(hp + 4);
          s0.x += h0.x; s0.y += h0.y; s0.z += h0.z; s0.w += h0.w;
          s1.x += h1.x; s1.y += h1.y; s1.z += h1.z; s1.w += h1.w;
        }
        float sc = inv[r];
        a[0] = s0.x * sc; a[1] = s0.y * sc; a[2] = s0.z * sc; a[3] = s0.w * sc;
        a[4] = s1.x * sc; a[5] = s1.y * sc; a[6] = s1.z * sc; a[7] = s1.w * sc;
      }
      const float* bp = Bbase + (size_t)(kk + lb_k) * D + col0 + lb_col;
      float4 b0 = *(const float4*)bp;
      float4 b1 = *(const float4*)(bp + 4);

      __syncthreads();
      As[la_k + 0][la_row] = a[0];
      As[la_k + 1][la_row] = a[1];
      As[la_k + 2][la_row] = a[2];
      As[la_k + 3][la_row] = a[3];
      As[la_k + 4][la_row] = a[4];
      As[la_k + 5][la_row] = a[5];
      As[la_k + 6][la_row] = a[6];
      As[la_k + 7][la_row] = a[7];
      *(float4*)&Bs[lb_k][lb_col] = b0;
      *(float4*)&Bs[lb_k][lb_col + 4] = b1;
      __syncthreads();

#pragma unroll
      for (int k = 0; k < BK; k++) {
        float4 a01 = *(float4*)&As[k][ty * 8];
        float4 a23 = *(float4*)&As[k][ty * 8 + 4];
        float4 b01 = *(float4*)&Bs[k][tx * 8];
        float4 b23 = *(float4*)&Bs[k][tx * 8 + 4];
        float av8[8] = {a01.x, a01.y, a01.z, a01.w, a23.x, a23.y, a23.z, a23.w};
        float bv8[8] = {b01.x, b01.y, b01.z, b01.w, b23.x, b23.y, b23.z, b23.w};
#pragma unroll
        for (int i = 0; i < 8; i++)
#pragma unroll
          for (int j = 0; j < 8; j++)
            acc[i][j] = fmaf(av8[i], bv8[j], acc[i][j]);
      }
    }
  }

  // epilogue: bias + ReLU
  float bb[8];
#pragma unroll
  for (int j = 0; j < 8; j++) bb[j] = bias[col0 + tx * 8 + j];

  const int crow = row0 + ty * 8;
#pragma unroll
  for (int i = 0; i < 8; i++) {
    int r = crow + i;
    if (r >= M) break;
    float* cp = C + (size_t)r * D + col0 + tx * 8;
    float4 v0, v1;
    v0.x = fmaxf(acc[i][0] + bb[0], 0.f);
    v0.y = fmaxf(acc[i][1] + bb[1], 0.f);
    v0.z = fmaxf(acc[i][2] + bb[2], 0.f);
    v0.w = fmaxf(acc[i][3] + bb[3], 0.f);
    v1.x = fmaxf(acc[i][4] + bb[4], 0.f);
    v1.y = fmaxf(acc[i][5] + bb[5], 0.f);
    v1.z = fmaxf(acc[i][6] + bb[6], 0.f);
    v1.w = fmaxf(acc[i][7] + bb[7], 0.f);
    *(float4*)cp = v0;
    *(float4*)(cp + 4) = v1;
  }
}

// ---------------- graph mean-pool: one block per graph, no atomics ---------
__global__ __launch_bounds__(256) void k_pool(const float* __restrict__ h,
    const int* __restrict__ gstart, float* __restrict__ gmean, int G) {
  __shared__ float red[4][D];
  int g = blockIdx.x;
  int lo = gstart[g], hi = gstart[g + 1];
  int tid = threadIdx.x, wave = tid >> 6, lane = tid & 63;
  float4 a = make_float4(0.f, 0.f, 0.f, 0.f);
  for (int i = lo + wave; i < hi; i += 4) {
    float4 v = *(const float4*)(h + (size_t)i * D + lane * 4);
    a.x += v.x; a.y += v.y; a.z += v.z; a.w += v.w;
  }
  *(float4*)&red[wave][lane * 4] = a;
  __syncthreads();
  float s = red[0][tid] + red[1][tid] + red[2][tid] + red[3][tid];
  float inv = (hi > lo) ? 1.0f / (float)(hi - lo) : 0.0f;
  gmean[(size_t)g * D + tid] = s * inv;
}

// ---------------- head: out[g][:] = gmean[g] @ lin_W + lin_b ----------------
__global__ __launch_bounds__(256) void k_final(const float* __restrict__ gmean,
    const float* __restrict__ linW, const float* __restrict__ linb,
    float* __restrict__ out, int G) {
  int g = blockIdx.x * 4 + (threadIdx.x >> 6);
  if (g >= G) return;
  int lane = threadIdx.x & 63;
  float4 v = *(const float4*)(gmean + (size_t)g * D + lane * 4);
  float vv[4] = {v.x, v.y, v.z, v.w};
  float a0 = 0.f, a1 = 0.f, a2 = 0.f, a3 = 0.f;
#pragma unroll
  for (int j = 0; j < 4; j++) {
    float4 w = *(const float4*)(linW + (lane * 4 + j) * 4);
    a0 = fmaf(vv[j], w.x, a0);
    a1 = fmaf(vv[j], w.y, a1);
    a2 = fmaf(vv[j], w.z, a2);
    a3 = fmaf(vv[j], w.w, a3);
  }
  for (int off = 32; off > 0; off >>= 1) {
    a0 += __shfl_down(a0, off, 64);
    a1 += __shfl_down(a1, off, 64);
    a2 += __shfl_down(a2, off, 64);
    a3 += __shfl_down(a3, off, 64);
  }
  if (lane == 0) {
    out[g * 4 + 0] = a0 + linb[0];
    out[g * 4 + 1] = a1 + linb[1];
    out[g * 4 + 2] = a2 + linb[2];
    out[g * 4 + 3] = a3 + linb[3];
  }
}

extern "C" void kernel_launch(void* const* d_in, const int* in_sizes, int n_in,
                              void* d_out, int out_size, void* d_ws, size_t ws_size,
                              hipStream_t stream) {
  const int*   x     = (const int*)d_in[0];
  const int*   ei    = (const int*)d_in[1];
  const int*   et    = (const int*)d_in[2];
  const int*   batch = (const int*)d_in[3];
  const float* table = (const float*)d_in[5];
  const float* W1    = (const float*)d_in[6];
  const float* root1 = (const float*)d_in[7];
  const float* b1    = (const float*)d_in[8];
  const float* W2    = (const float*)d_in[9];
  const float* root2 = (const float*)d_in[10];
  const float* b2    = (const float*)d_in[11];
  const float* linW  = (const float*)d_in[12];
  const float* linb  = (const float*)d_in[13];
  float* out = (float*)d_out;

  const int N = in_sizes[0];
  const int E = in_sizes[2];
  const int G = out_size / 4;
  const int* src = ei;
  const int* dst = ei + E;
  const int RN = 3 * N;

  // ws layout (~208 MB, round-2-proven footprint):
  // bufA(N*D f32) | bufB(N*D f32) | gmean(G*D f32) | off(3N+1) | es(E) | gstart(G+1)
  // cur(3N) and bsum alias the (not-yet-live) bufA region.
  float* ws = (float*)d_ws;
  size_t nh = (size_t)N * D;
  float* bufA  = ws;
  float* bufB  = bufA + nh;
  float* gmean = bufB + nh;
  int*   off    = (int*)(gmean + (size_t)G * D);
  int*   es     = off + (RN + 1);
  int*   gstart = es + E;
  int*   cur    = (int*)bufA;        // dead before k_lgemm writes bufA
  int*   bsum   = cur + RN;

  const int nb = (RN + SB - 1) / SB;

  // ---- CSR by (relation, dst) ----
  k_zero_i<<<(RN + 255) / 256, 256, 0, stream>>>(cur, RN);
  k_count_i<<<(E + 255) / 256, 256, 0, stream>>>(dst, et, cur, E, N);
  k_scan1<<<nb, 256, 0, stream>>>(cur, bsum, RN);
  k_scan2<<<1, 64, 0, stream>>>(bsum, nb, off + RN);
  k_scan3<<<nb, 256, 0, stream>>>(cur, bsum, off, cur, RN);  // off=cur=excl scan
  k_place2<<<(E + 255) / 256, 256, 0, stream>>>(src, dst, et, cur, es, E, N);
  k_bounds<<<(N + 255) / 256, 256, 0, stream>>>(batch, gstart, N, G);

  dim3 gg((N + BM - 1) / BM, D / BN);

  // ---- layer 1: h = table[x]; out -> bufA (ReLU fused) ----
  k_lgemm<<<gg, 256, 0, stream>>>(table, x, table, x, es, off,
                                  root1, W1, b1, bufA, N, N);
  // ---- layer 2: h = bufA; out -> bufB (ReLU fused) ----
  k_lgemm<<<gg, 256, 0, stream>>>(bufA, nullptr, bufA, nullptr, es, off,
                                  root2, W2, b2, bufB, N, N);

  // ---- pool + head ----
  k_pool<<<G, 256, 0, stream>>>(bufB, gstart, gmean, G);
  k_final<<<(G + 3) / 4, 256, 0, stream>>>(gmean, linW, linb, out, G);
}

// Round 5
// 645.982 us; speedup vs baseline: 11.4579x; 3.1324x over previous
//
#include <hip/hip_runtime.h>

#define D 256
#define SB 1024
typedef __attribute__((ext_vector_type(8))) short short8;
typedef __attribute__((ext_vector_type(4))) float floatx4;

__device__ __forceinline__ unsigned short f2bf(float f) {
  unsigned int u = __float_as_uint(f);
  u = (u + 0x7FFF + ((u >> 16) & 1)) >> 16;   // RNE
  return (unsigned short)u;
}
__device__ __forceinline__ float bf2f(unsigned short h) {
  return __uint_as_float(((unsigned int)h) << 16);
}

// ---------------- setup kernels (proven in round 4) ----------------
__global__ __launch_bounds__(256) void k_zero_i(int* __restrict__ p, int n) {
  int i = blockIdx.x * 256 + threadIdx.x;
  if (i < n) p[i] = 0;
}

__global__ __launch_bounds__(256) void k_count_i(const int* __restrict__ dst,
    const int* __restrict__ et, int* __restrict__ cnt, int E, int N) {
  int e = blockIdx.x * 256 + threadIdx.x;
  if (e >= E) return;
  atomicAdd(&cnt[et[e] * N + dst[e]], 1);
}

__global__ __launch_bounds__(256) void k_scan1(const int* __restrict__ in,
    int* __restrict__ bsum, int n) {
  __shared__ int s[256];
  int base = blockIdx.x * SB, t = threadIdx.x;
  int a = 0;
#pragma unroll
  for (int j = 0; j < 4; j++) { int i = base + t * 4 + j; if (i < n) a += in[i]; }
  s[t] = a; __syncthreads();
  for (int o = 128; o > 0; o >>= 1) { if (t < o) s[t] += s[t + o]; __syncthreads(); }
  if (t == 0) bsum[blockIdx.x] = s[0];
}

__global__ void k_scan2(int* __restrict__ bsum, int nb, int* __restrict__ total_out) {
  if (threadIdx.x == 0 && blockIdx.x == 0) {
    int acc = 0;
    for (int i = 0; i < nb; i++) { int v = bsum[i]; bsum[i] = acc; acc += v; }
    *total_out = acc;
  }
}

__global__ __launch_bounds__(256) void k_scan3(const int* __restrict__ in,
    const int* __restrict__ bsum, int* __restrict__ off, int* __restrict__ cur,
    int n) {
  __shared__ int s[256];
  int base = blockIdx.x * SB, t = threadIdx.x;
  int v[4]; int a = 0;
#pragma unroll
  for (int j = 0; j < 4; j++) {
    int i = base + t * 4 + j;
    v[j] = (i < n) ? in[i] : 0;
    a += v[j];
  }
  s[t] = a; __syncthreads();
  for (int o = 1; o < 256; o <<= 1) {
    int x_ = (t >= o) ? s[t - o] : 0;
    __syncthreads();
    s[t] += x_;
    __syncthreads();
  }
  int excl = (t > 0 ? s[t - 1] : 0) + bsum[blockIdx.x];
#pragma unroll
  for (int j = 0; j < 4; j++) {
    int i = base + t * 4 + j;
    if (i < n) { off[i] = excl; cur[i] = excl; excl += v[j]; }
  }
}

__global__ __launch_bounds__(256) void k_place2(const int* __restrict__ src,
    const int* __restrict__ dst, const int* __restrict__ et,
    int* __restrict__ cur, int* __restrict__ es, int E, int N) {
  int e = blockIdx.x * 256 + threadIdx.x;
  if (e >= E) return;
  int pos = atomicAdd(&cur[et[e] * N + dst[e]], 1);
  es[pos] = src[e];
}

__global__ __launch_bounds__(256) void k_bounds(const int* __restrict__ batch,
    int* __restrict__ gstart, int N, int G) {
  int i = blockIdx.x * 256 + threadIdx.x;
  if (i >= N) return;
  int b = batch[i];
  if (i == 0) { for (int g = 0; g <= b; g++) gstart[g] = 0; }
  else { int pb = batch[i - 1]; for (int g = pb + 1; g <= b; g++) gstart[g] = i; }
  if (i == N - 1) { for (int g = b + 1; g <= G; g++) gstart[g] = N; }
}

// ---------------- fp32 -> bf16 table ----------------
__global__ __launch_bounds__(256) void k_cvt(const float* __restrict__ src,
    unsigned short* __restrict__ dstb, int n) {
  int i = blockIdx.x * 256 + threadIdx.x;
  if (i < n) dstb[i] = f2bf(src[i]);
}

// ---------------- weights -> bf16, transposed to [mat][n][k] ----------------
__global__ __launch_bounds__(256) void k_cvt_w(const float* __restrict__ root,
    const float* __restrict__ W, unsigned short* __restrict__ wb) {
  int idx = blockIdx.x * 256 + threadIdx.x;   // 4*65536
  if (idx >= 4 * 65536) return;
  int mat = idx >> 16, rem = idx & 65535;
  int n = rem >> 8, k = rem & 255;
  const float* s = (mat == 0) ? root : (W + (size_t)(mat - 1) * 65536);
  wb[idx] = f2bf(s[k * 256 + n]);
}

// ---------------- relation aggregation: out[r*N+i] = invc * sum h[src] -----
// one wave per (rel,node); h bf16, out bf16
__global__ __launch_bounds__(256) void k_agg(const unsigned short* __restrict__ h,
    const int* __restrict__ gidx, const int* __restrict__ es,
    const int* __restrict__ off, unsigned short* __restrict__ out, int RN) {
  int id = blockIdx.x * 4 + (threadIdx.x >> 6);
  if (id >= RN) return;
  int lane = threadIdx.x & 63;
  int lo = off[id], hi = off[id + 1];
  float inv = 1.0f / (float)((hi - lo) > 0 ? (hi - lo) : 1);
  float a0 = 0.f, a1 = 0.f, a2 = 0.f, a3 = 0.f;
  for (int p = lo; p < hi; ++p) {
    int s = es[p];
    int row = gidx ? gidx[s] : s;
    ushort4 v = *(const ushort4*)(h + (size_t)row * D + lane * 4);
    a0 += bf2f(v.x); a1 += bf2f(v.y); a2 += bf2f(v.z); a3 += bf2f(v.w);
  }
  ushort4 o;
  o.x = f2bf(a0 * inv); o.y = f2bf(a1 * inv);
  o.z = f2bf(a2 * inv); o.w = f2bf(a3 * inv);
  *(ushort4*)(out + (size_t)id * D + lane * 4) = o;
}

// ---------------- fused K=1024 bf16 MFMA GEMM ----------------
// C[i,:] = relu(bias + Aroot[rowA(i)]@Wb[0] + sum_r agg[r*N+i]@Wb[r+1])
// block: 256 thr = 4 waves, 64 rows x 256 cols (full width -> epilogue may
// write over an input page: each block writes only rows it alone reads).
__global__ __launch_bounds__(256) void k_lgemm(
    const unsigned short* __restrict__ Aroot, const int* __restrict__ gidx,
    const unsigned short* agg, const unsigned short* __restrict__ wb,
    const float* __restrict__ bias, unsigned short* Cout, int M, int N) {
  __shared__ unsigned short AsU[64 * 32];        // 4 KB  [row][k]
  __shared__ unsigned short BsU[256 * 40];       // 20 KB [n][k+pad8]
  const int tid = threadIdx.x;
  const int w = tid >> 6, lane = tid & 63;
  const int i0 = blockIdx.x * 64;
  const int ml = lane & 15, q = lane >> 4;

  // A staging coords: thread t -> row tid>>2, 16B chunk tid&3
  const int arow = tid >> 2, achunk = tid & 3;
  const int gr = i0 + arow;
  const int grc = (gr < M) ? gr : (M - 1);
  const int rowA0 = gidx ? gidx[grc] : grc;
  const unsigned short* abase[4];
  abase[0] = Aroot + (size_t)rowA0 * D + achunk * 8;
  abase[1] = agg + ((size_t)0 * N + grc) * D + achunk * 8;
  abase[2] = agg + ((size_t)1 * N + grc) * D + achunk * 8;
  abase[3] = agg + ((size_t)2 * N + grc) * D + achunk * 8;

  floatx4 acc[4][4];
#pragma unroll
  for (int i = 0; i < 4; i++)
#pragma unroll
    for (int j = 0; j < 4; j++) acc[i][j] = (floatx4){0.f, 0.f, 0.f, 0.f};

  for (int seg = 0; seg < 4; ++seg) {
    const unsigned short* ab = abase[seg];
    const unsigned short* bb = wb + (size_t)seg * 65536 + (size_t)tid * D;
    for (int kt2 = 0; kt2 < 8; ++kt2) {
      const int kloc = kt2 * 32;
      uint4 av = *(const uint4*)(ab + kloc);
      uint4 bv0 = *(const uint4*)(bb + kloc + 0);
      uint4 bv1 = *(const uint4*)(bb + kloc + 8);
      uint4 bv2 = *(const uint4*)(bb + kloc + 16);
      uint4 bv3 = *(const uint4*)(bb + kloc + 24);
      __syncthreads();
      *(uint4*)&AsU[arow * 32 + achunk * 8] = av;
      *(uint4*)&BsU[tid * 40 + 0] = bv0;
      *(uint4*)&BsU[tid * 40 + 8] = bv1;
      *(uint4*)&BsU[tid * 40 + 16] = bv2;
      *(uint4*)&BsU[tid * 40 + 24] = bv3;
      __syncthreads();

      short8 aF[4], bF[4];
#pragma unroll
      for (int mi = 0; mi < 4; mi++)
        aF[mi] = *(const short8*)&AsU[(mi * 16 + ml) * 32 + q * 8];
#pragma unroll
      for (int ni = 0; ni < 4; ni++)
        bF[ni] = *(const short8*)&BsU[(w * 64 + ni * 16 + ml) * 40 + q * 8];
#pragma unroll
      for (int mi = 0; mi < 4; mi++)
#pragma unroll
        for (int ni = 0; ni < 4; ni++)
          acc[mi][ni] = __builtin_amdgcn_mfma_f32_16x16x32_bf16(
              aF[mi], bF[ni], acc[mi][ni], 0, 0, 0);
    }
  }

  // epilogue: bias + ReLU + bf16; C/D layout col=lane&15, row=q*4+reg
  float bv[4];
#pragma unroll
  for (int ni = 0; ni < 4; ni++) bv[ni] = bias[w * 64 + ni * 16 + ml];
#pragma unroll
  for (int mi = 0; mi < 4; mi++) {
#pragma unroll
    for (int ni = 0; ni < 4; ni++) {
      int col = w * 64 + ni * 16 + ml;
#pragma unroll
      for (int j = 0; j < 4; j++) {
        int row = i0 + mi * 16 + q * 4 + j;
        if (row < M) {
          float v = fmaxf(acc[mi][ni][j] + bv[ni], 0.f);
          Cout[(size_t)row * D + col] = f2bf(v);
        }
      }
    }
  }
}

// ---------------- graph mean-pool (bf16 in, fp32 out) ----------------
__global__ __launch_bounds__(256) void k_pool(const unsigned short* __restrict__ h,
    const int* __restrict__ gstart, float* __restrict__ gmean, int G) {
  __shared__ float red[4][D];
  int g = blockIdx.x;
  int lo = gstart[g], hi = gstart[g + 1];
  int tid = threadIdx.x, wave = tid >> 6, lane = tid & 63;
  float a0 = 0.f, a1 = 0.f, a2 = 0.f, a3 = 0.f;
  for (int i = lo + wave; i < hi; i += 4) {
    ushort4 v = *(const ushort4*)(h + (size_t)i * D + lane * 4);
    a0 += bf2f(v.x); a1 += bf2f(v.y); a2 += bf2f(v.z); a3 += bf2f(v.w);
  }
  red[wave][lane * 4 + 0] = a0;
  red[wave][lane * 4 + 1] = a1;
  red[wave][lane * 4 + 2] = a2;
  red[wave][lane * 4 + 3] = a3;
  __syncthreads();
  float s = red[0][tid] + red[1][tid] + red[2][tid] + red[3][tid];
  float inv = (hi > lo) ? 1.0f / (float)(hi - lo) : 0.0f;
  gmean[(size_t)g * D + tid] = s * inv;
}

// ---------------- head ----------------
__global__ __launch_bounds__(256) void k_final(const float* __restrict__ gmean,
    const float* __restrict__ linW, const float* __restrict__ linb,
    float* __restrict__ out, int G) {
  int g = blockIdx.x * 4 + (threadIdx.x >> 6);
  if (g >= G) return;
  int lane = threadIdx.x & 63;
  float4 v = *(const float4*)(gmean + (size_t)g * D + lane * 4);
  float vv[4] = {v.x, v.y, v.z, v.w};
  float a0 = 0.f, a1 = 0.f, a2 = 0.f, a3 = 0.f;
#pragma unroll
  for (int j = 0; j < 4; j++) {
    float4 wv = *(const float4*)(linW + (lane * 4 + j) * 4);
    a0 = fmaf(vv[j], wv.x, a0);
    a1 = fmaf(vv[j], wv.y, a1);
    a2 = fmaf(vv[j], wv.z, a2);
    a3 = fmaf(vv[j], wv.w, a3);
  }
  for (int o = 32; o > 0; o >>= 1) {
    a0 += __shfl_down(a0, o, 64);
    a1 += __shfl_down(a1, o, 64);
    a2 += __shfl_down(a2, o, 64);
    a3 += __shfl_down(a3, o, 64);
  }
  if (lane == 0) {
    out[g * 4 + 0] = a0 + linb[0];
    out[g * 4 + 1] = a1 + linb[1];
    out[g * 4 + 2] = a2 + linb[2];
    out[g * 4 + 3] = a3 + linb[3];
  }
}

extern "C" void kernel_launch(void* const* d_in, const int* in_sizes, int n_in,
                              void* d_out, int out_size, void* d_ws, size_t ws_size,
                              hipStream_t stream) {
  const int*   x     = (const int*)d_in[0];
  const int*   ei    = (const int*)d_in[1];
  const int*   et    = (const int*)d_in[2];
  const int*   batch = (const int*)d_in[3];
  const float* table = (const float*)d_in[5];
  const float* W1    = (const float*)d_in[6];
  const float* root1 = (const float*)d_in[7];
  const float* b1    = (const float*)d_in[8];
  const float* W2    = (const float*)d_in[9];
  const float* root2 = (const float*)d_in[10];
  const float* b2    = (const float*)d_in[11];
  const float* linW  = (const float*)d_in[12];
  const float* linb  = (const float*)d_in[13];
  float* out = (float*)d_out;

  const int N = in_sizes[0];
  const int E = in_sizes[2];
  const int G = out_size / 4;
  const int VOC = in_sizes[5] / D;
  const int* src = ei;
  const int* dst = ei + E;
  const int RN = 3 * N;

  // ---- ws layout (~209 MB) ----
  // pages P0..P3: N*D bf16 each (51.2 MB). misc after pages.
  // Aliases: cur/bsum overlay P0 (dead during setup); tableb overlays P3
  // (dead before L2 agg writes P3).
  // L1: agg(tableb)->P0,P1,P2 ; lgemm1(tableb root) writes h1 over P0.
  // L2: agg(P0)->P1,P2,P3 ; lgemm2(P0 root) writes h2 over P1. pool(P1).
  char* wsb = (char*)d_ws;
  size_t pg = (size_t)N * D * 2;
  unsigned short* P0 = (unsigned short*)wsb;
  unsigned short* P1 = (unsigned short*)(wsb + pg);
  unsigned short* P3 = (unsigned short*)(wsb + 3 * pg);
  unsigned short* wb = (unsigned short*)(wsb + 4 * pg);  // 2 layers x 4 mats
  int*   off    = (int*)(wb + 2 * 4 * 65536);
  int*   es     = off + (RN + 1);
  int*   gstart = es + E;
  float* gmean  = (float*)(gstart + (G + 1));
  unsigned short* tableb = P3;          // alias
  int* cur  = (int*)P0;                 // alias
  int* bsum = cur + RN;                 // alias

  const int nb = (RN + SB - 1) / SB;

  // ---- CSR by (relation, dst) + graph bounds + dtype prep ----
  k_zero_i<<<(RN + 255) / 256, 256, 0, stream>>>(cur, RN);
  k_count_i<<<(E + 255) / 256, 256, 0, stream>>>(dst, et, cur, E, N);
  k_scan1<<<nb, 256, 0, stream>>>(cur, bsum, RN);
  k_scan2<<<1, 64, 0, stream>>>(bsum, nb, off + RN);
  k_scan3<<<nb, 256, 0, stream>>>(cur, bsum, off, cur, RN);
  k_place2<<<(E + 255) / 256, 256, 0, stream>>>(src, dst, et, cur, es, E, N);
  k_bounds<<<(N + 255) / 256, 256, 0, stream>>>(batch, gstart, N, G);
  k_cvt<<<(VOC * D + 255) / 256, 256, 0, stream>>>(table, tableb, VOC * D);
  k_cvt_w<<<(4 * 65536 + 255) / 256, 256, 0, stream>>>(root1, W1, wb);
  k_cvt_w<<<(4 * 65536 + 255) / 256, 256, 0, stream>>>(root2, W2, wb + 4 * 65536);

  const int gagg = (RN + 3) / 4;
  const int ggemm = (N + 63) / 64;

  // ---- layer 1 ----
  k_agg<<<gagg, 256, 0, stream>>>(tableb, x, es, off, P0, RN);
  k_lgemm<<<ggemm, 256, 0, stream>>>(tableb, x, P0, wb, b1, P0, N, N);
  // ---- layer 2 ----
  k_agg<<<gagg, 256, 0, stream>>>(P0, nullptr, es, off, P1, RN);
  k_lgemm<<<ggemm, 256, 0, stream>>>(P0, nullptr, P1, wb + 4 * 65536, b2, P1, N, N);

  // ---- pool + head ----
  k_pool<<<G, 256, 0, stream>>>(P1, gstart, gmean, G);
  k_final<<<(G + 3) / 4, 256, 0, stream>>>(gmean, linW, linb, out, G);
}

// Round 6
// 577.703 us; speedup vs baseline: 12.8122x; 1.1182x over previous
//
#include <hip/hip_runtime.h>

#define D 256
#define SB 1024
typedef __attribute__((ext_vector_type(8))) short short8;
typedef __attribute__((ext_vector_type(4))) float floatx4;

__device__ __forceinline__ unsigned short f2bf(float f) {
  unsigned int u = __float_as_uint(f);
  u = (u + 0x7FFF + ((u >> 16) & 1)) >> 16;   // RNE
  return (unsigned short)u;
}
__device__ __forceinline__ float bf2f(unsigned short h) {
  return __uint_as_float(((unsigned int)h) << 16);
}

// ---------------- setup kernels ----------------
__global__ __launch_bounds__(256) void k_zero_i(int* __restrict__ p, int n) {
  int i = blockIdx.x * 256 + threadIdx.x;
  if (i < n) p[i] = 0;
}

__global__ __launch_bounds__(256) void k_count_i(const int* __restrict__ dst,
    const int* __restrict__ et, int* __restrict__ cnt, int E, int N) {
  int e = blockIdx.x * 256 + threadIdx.x;
  if (e >= E) return;
  atomicAdd(&cnt[et[e] * N + dst[e]], 1);
}

__global__ __launch_bounds__(256) void k_scan1(const int* __restrict__ in,
    int* __restrict__ bsum, int n) {
  __shared__ int s[256];
  int base = blockIdx.x * SB, t = threadIdx.x;
  int a = 0;
#pragma unroll
  for (int j = 0; j < 4; j++) { int i = base + t * 4 + j; if (i < n) a += in[i]; }
  s[t] = a; __syncthreads();
  for (int o = 128; o > 0; o >>= 1) { if (t < o) s[t] += s[t + o]; __syncthreads(); }
  if (t == 0) bsum[blockIdx.x] = s[0];
}

// parallel single-block exclusive scan over bsum (nb <= 1024)
__global__ __launch_bounds__(256) void k_scan2(int* __restrict__ bsum, int nb,
    int* __restrict__ total_out) {
  __shared__ int s[256];
  int t = threadIdx.x;
  int v[4]; int a = 0;
#pragma unroll
  for (int j = 0; j < 4; j++) {
    int i = t * 4 + j;
    v[j] = (i < nb) ? bsum[i] : 0;
    a += v[j];
  }
  s[t] = a; __syncthreads();
  for (int o = 1; o < 256; o <<= 1) {
    int x_ = (t >= o) ? s[t - o] : 0;
    __syncthreads();
    s[t] += x_;
    __syncthreads();
  }
  int excl = (t > 0) ? s[t - 1] : 0;
#pragma unroll
  for (int j = 0; j < 4; j++) {
    int i = t * 4 + j;
    if (i < nb) { bsum[i] = excl; excl += v[j]; }
  }
  if (t == 255) *total_out = s[255];
}

__global__ __launch_bounds__(256) void k_scan3(const int* __restrict__ in,
    const int* __restrict__ bsum, int* __restrict__ off, int* __restrict__ cur,
    int n) {
  __shared__ int s[256];
  int base = blockIdx.x * SB, t = threadIdx.x;
  int v[4]; int a = 0;
#pragma unroll
  for (int j = 0; j < 4; j++) {
    int i = base + t * 4 + j;
    v[j] = (i < n) ? in[i] : 0;
    a += v[j];
  }
  s[t] = a; __syncthreads();
  for (int o = 1; o < 256; o <<= 1) {
    int x_ = (t >= o) ? s[t - o] : 0;
    __syncthreads();
    s[t] += x_;
    __syncthreads();
  }
  int excl = (t > 0 ? s[t - 1] : 0) + bsum[blockIdx.x];
#pragma unroll
  for (int j = 0; j < 4; j++) {
    int i = base + t * 4 + j;
    if (i < n) { off[i] = excl; cur[i] = excl; excl += v[j]; }
  }
}

__global__ __launch_bounds__(256) void k_place2(const int* __restrict__ src,
    const int* __restrict__ dst, const int* __restrict__ et,
    int* __restrict__ cur, int* __restrict__ es, int E, int N) {
  int e = blockIdx.x * 256 + threadIdx.x;
  if (e >= E) return;
  int pos = atomicAdd(&cur[et[e] * N + dst[e]], 1);
  es[pos] = src[e];
}

__global__ __launch_bounds__(256) void k_bounds(const int* __restrict__ batch,
    int* __restrict__ gstart, int N, int G) {
  int i = blockIdx.x * 256 + threadIdx.x;
  if (i >= N) return;
  int b = batch[i];
  if (i == 0) { for (int g = 0; g <= b; g++) gstart[g] = 0; }
  else { int pb = batch[i - 1]; for (int g = pb + 1; g <= b; g++) gstart[g] = i; }
  if (i == N - 1) { for (int g = b + 1; g <= G; g++) gstart[g] = N; }
}

// ---------------- fp32 -> bf16 table ----------------
__global__ __launch_bounds__(256) void k_cvt(const float* __restrict__ src,
    unsigned short* __restrict__ dstb, int n) {
  int i = blockIdx.x * 256 + threadIdx.x;
  if (i < n) dstb[i] = f2bf(src[i]);
}

// ---------------- weights -> bf16, transposed to [mat][n][k] ----------------
__global__ __launch_bounds__(256) void k_cvt_w(const float* __restrict__ root,
    const float* __restrict__ W, unsigned short* __restrict__ wb) {
  int idx = blockIdx.x * 256 + threadIdx.x;   // 4*65536
  if (idx >= 4 * 65536) return;
  int mat = idx >> 16, rem = idx & 65535;
  int n = rem >> 8, k = rem & 255;
  const float* s = (mat == 0) ? root : (W + (size_t)(mat - 1) * 65536);
  wb[idx] = f2bf(s[k * 256 + n]);
}

// ---------------- relation aggregation: out[r*N+i] = invc * sum h[src] -----
__global__ __launch_bounds__(256) void k_agg(const unsigned short* __restrict__ h,
    const int* __restrict__ gidx, const int* __restrict__ es,
    const int* __restrict__ off, unsigned short* __restrict__ out, int RN) {
  int id = blockIdx.x * 4 + (threadIdx.x >> 6);
  if (id >= RN) return;
  int lane = threadIdx.x & 63;
  int lo = off[id], hi = off[id + 1];
  float inv = 1.0f / (float)((hi - lo) > 0 ? (hi - lo) : 1);
  float a0 = 0.f, a1 = 0.f, a2 = 0.f, a3 = 0.f;
  for (int p = lo; p < hi; ++p) {
    int s = es[p];
    int row = gidx ? gidx[s] : s;
    ushort4 v = *(const ushort4*)(h + (size_t)row * D + lane * 4);
    a0 += bf2f(v.x); a1 += bf2f(v.y); a2 += bf2f(v.z); a3 += bf2f(v.w);
  }
  ushort4 o;
  o.x = f2bf(a0 * inv); o.y = f2bf(a1 * inv);
  o.z = f2bf(a2 * inv); o.w = f2bf(a3 * inv);
  *(ushort4*)(out + (size_t)id * D + lane * 4) = o;
}

// ---------------- fused K=1024 bf16 MFMA GEMM, software-pipelined ----------
// C[i,:] = relu(bias + Aroot[rowA(i)]@Wb[0] + sum_r agg[r*N+i]@Wb[r+1])
// 64 rows x 256 cols per block. AsU padded to stride 40 (2-way banks = free).
// Step s+1's global loads issue right after barrier #2 and fly under compute.
__global__ __launch_bounds__(256) void k_lgemm(
    const unsigned short* __restrict__ Aroot, const int* __restrict__ gidx,
    const unsigned short* agg, const unsigned short* __restrict__ wb,
    const float* __restrict__ bias, unsigned short* Cout, int M, int N) {
  __shared__ unsigned short AsU[64 * 40];        // 5 KB  [row][k] pad->40
  __shared__ unsigned short BsU[256 * 40];       // 20 KB [n][k+pad8]
  const int tid = threadIdx.x;
  const int w = tid >> 6, lane = tid & 63;
  const int i0 = blockIdx.x * 64;
  const int ml = lane & 15, q = lane >> 4;

  const int arow = tid >> 2, achunk = tid & 3;
  const int gr = i0 + arow;
  const int grc = (gr < M) ? gr : (M - 1);
  const int rowA0 = gidx ? gidx[grc] : grc;
  const unsigned short* abase[4];
  abase[0] = Aroot + (size_t)rowA0 * D + achunk * 8;
  abase[1] = agg + ((size_t)0 * N + grc) * D + achunk * 8;
  abase[2] = agg + ((size_t)1 * N + grc) * D + achunk * 8;
  abase[3] = agg + ((size_t)2 * N + grc) * D + achunk * 8;

  floatx4 acc[4][4];
#pragma unroll
  for (int i = 0; i < 4; i++)
#pragma unroll
    for (int j = 0; j < 4; j++) acc[i][j] = (floatx4){0.f, 0.f, 0.f, 0.f};

  // prefetch registers
  uint4 av, bv0, bv1, bv2, bv3;
  {
    const unsigned short* ab = abase[0];
    const unsigned short* bb = wb + (size_t)tid * D;
    av  = *(const uint4*)(ab);
    bv0 = *(const uint4*)(bb + 0);
    bv1 = *(const uint4*)(bb + 8);
    bv2 = *(const uint4*)(bb + 16);
    bv3 = *(const uint4*)(bb + 24);
  }

  for (int step = 0; step < 32; ++step) {
    __syncthreads();   // previous step's LDS consumers done
    *(uint4*)&AsU[arow * 40 + achunk * 8] = av;
    *(uint4*)&BsU[tid * 40 + 0] = bv0;
    *(uint4*)&BsU[tid * 40 + 8] = bv1;
    *(uint4*)&BsU[tid * 40 + 16] = bv2;
    *(uint4*)&BsU[tid * 40 + 24] = bv3;
    __syncthreads();

    // issue next step's loads now — they fly under the compute below
    {
      int ns = (step < 31) ? step + 1 : 31;
      int seg = ns >> 3, kloc = (ns & 7) * 32;
      const unsigned short* ab = abase[seg] + kloc;
      const unsigned short* bb = wb + (size_t)seg * 65536 + (size_t)tid * D + kloc;
      av  = *(const uint4*)(ab);
      bv0 = *(const uint4*)(bb + 0);
      bv1 = *(const uint4*)(bb + 8);
      bv2 = *(const uint4*)(bb + 16);
      bv3 = *(const uint4*)(bb + 24);
    }

    short8 aF[4], bF[4];
#pragma unroll
    for (int mi = 0; mi < 4; mi++)
      aF[mi] = *(const short8*)&AsU[(mi * 16 + ml) * 40 + q * 8];
#pragma unroll
    for (int ni = 0; ni < 4; ni++)
      bF[ni] = *(const short8*)&BsU[(w * 64 + ni * 16 + ml) * 40 + q * 8];
#pragma unroll
    for (int mi = 0; mi < 4; mi++)
#pragma unroll
      for (int ni = 0; ni < 4; ni++)
        acc[mi][ni] = __builtin_amdgcn_mfma_f32_16x16x32_bf16(
            aF[mi], bF[ni], acc[mi][ni], 0, 0, 0);
  }

  // epilogue: bias + ReLU + bf16; C/D layout col=lane&15, row=q*4+reg
  float bv[4];
#pragma unroll
  for (int ni = 0; ni < 4; ni++) bv[ni] = bias[w * 64 + ni * 16 + ml];
#pragma unroll
  for (int mi = 0; mi < 4; mi++) {
#pragma unroll
    for (int ni = 0; ni < 4; ni++) {
      int col = w * 64 + ni * 16 + ml;
#pragma unroll
      for (int j = 0; j < 4; j++) {
        int row = i0 + mi * 16 + q * 4 + j;
        if (row < M) {
          float v = fmaxf(acc[mi][ni][j] + bv[ni], 0.f);
          Cout[(size_t)row * D + col] = f2bf(v);
        }
      }
    }
  }
}

// ---------------- graph mean-pool (bf16 in, fp32 out) ----------------
__global__ __launch_bounds__(256) void k_pool(const unsigned short* __restrict__ h,
    const int* __restrict__ gstart, float* __restrict__ gmean, int G) {
  __shared__ float red[4][D];
  int g = blockIdx.x;
  int lo = gstart[g], hi = gstart[g + 1];
  int tid = threadIdx.x, wave = tid >> 6, lane = tid & 63;
  float a0 = 0.f, a1 = 0.f, a2 = 0.f, a3 = 0.f;
  for (int i = lo + wave; i < hi; i += 4) {
    ushort4 v = *(const ushort4*)(h + (size_t)i * D + lane * 4);
    a0 += bf2f(v.x); a1 += bf2f(v.y); a2 += bf2f(v.z); a3 += bf2f(v.w);
  }
  red[wave][lane * 4 + 0] = a0;
  red[wave][lane * 4 + 1] = a1;
  red[wave][lane * 4 + 2] = a2;
  red[wave][lane * 4 + 3] = a3;
  __syncthreads();
  float s = red[0][tid] + red[1][tid] + red[2][tid] + red[3][tid];
  float inv = (hi > lo) ? 1.0f / (float)(hi - lo) : 0.0f;
  gmean[(size_t)g * D + tid] = s * inv;
}

// ---------------- head ----------------
__global__ __launch_bounds__(256) void k_final(const float* __restrict__ gmean,
    const float* __restrict__ linW, const float* __restrict__ linb,
    float* __restrict__ out, int G) {
  int g = blockIdx.x * 4 + (threadIdx.x >> 6);
  if (g >= G) return;
  int lane = threadIdx.x & 63;
  float4 v = *(const float4*)(gmean + (size_t)g * D + lane * 4);
  float vv[4] = {v.x, v.y, v.z, v.w};
  float a0 = 0.f, a1 = 0.f, a2 = 0.f, a3 = 0.f;
#pragma unroll
  for (int j = 0; j < 4; j++) {
    float4 wv = *(const float4*)(linW + (lane * 4 + j) * 4);
    a0 = fmaf(vv[j], wv.x, a0);
    a1 = fmaf(vv[j], wv.y, a1);
    a2 = fmaf(vv[j], wv.z, a2);
    a3 = fmaf(vv[j], wv.w, a3);
  }
  for (int o = 32; o > 0; o >>= 1) {
    a0 += __shfl_down(a0, o, 64);
    a1 += __shfl_down(a1, o, 64);
    a2 += __shfl_down(a2, o, 64);
    a3 += __shfl_down(a3, o, 64);
  }
  if (lane == 0) {
    out[g * 4 + 0] = a0 + linb[0];
    out[g * 4 + 1] = a1 + linb[1];
    out[g * 4 + 2] = a2 + linb[2];
    out[g * 4 + 3] = a3 + linb[3];
  }
}

extern "C" void kernel_launch(void* const* d_in, const int* in_sizes, int n_in,
                              void* d_out, int out_size, void* d_ws, size_t ws_size,
                              hipStream_t stream) {
  const int*   x     = (const int*)d_in[0];
  const int*   ei    = (const int*)d_in[1];
  const int*   et    = (const int*)d_in[2];
  const int*   batch = (const int*)d_in[3];
  const float* table = (const float*)d_in[5];
  const float* W1    = (const float*)d_in[6];
  const float* root1 = (const float*)d_in[7];
  const float* b1    = (const float*)d_in[8];
  const float* W2    = (const float*)d_in[9];
  const float* root2 = (const float*)d_in[10];
  const float* b2    = (const float*)d_in[11];
  const float* linW  = (const float*)d_in[12];
  const float* linb  = (const float*)d_in[13];
  float* out = (float*)d_out;

  const int N = in_sizes[0];
  const int E = in_sizes[2];
  const int G = out_size / 4;
  const int VOC = in_sizes[5] / D;
  const int* src = ei;
  const int* dst = ei + E;
  const int RN = 3 * N;

  // ---- ws layout (~209 MB), same proven aliasing as round 5 ----
  char* wsb = (char*)d_ws;
  size_t pg = (size_t)N * D * 2;
  unsigned short* P0 = (unsigned short*)wsb;
  unsigned short* P1 = (unsigned short*)(wsb + pg);
  unsigned short* P3 = (unsigned short*)(wsb + 3 * pg);
  unsigned short* wb = (unsigned short*)(wsb + 4 * pg);  // 2 layers x 4 mats
  int*   off    = (int*)(wb + 2 * 4 * 65536);
  int*   es     = off + (RN + 1);
  int*   gstart = es + E;
  float* gmean  = (float*)(gstart + (G + 1));
  unsigned short* tableb = P3;          // alias
  int* cur  = (int*)P0;                 // alias
  int* bsum = cur + RN;                 // alias

  const int nb = (RN + SB - 1) / SB;    // 293 <= 1024

  // ---- CSR by (relation, dst) + graph bounds + dtype prep ----
  k_zero_i<<<(RN + 255) / 256, 256, 0, stream>>>(cur, RN);
  k_count_i<<<(E + 255) / 256, 256, 0, stream>>>(dst, et, cur, E, N);
  k_scan1<<<nb, 256, 0, stream>>>(cur, bsum, RN);
  k_scan2<<<1, 256, 0, stream>>>(bsum, nb, off + RN);
  k_scan3<<<nb, 256, 0, stream>>>(cur, bsum, off, cur, RN);
  k_place2<<<(E + 255) / 256, 256, 0, stream>>>(src, dst, et, cur, es, E, N);
  k_bounds<<<(N + 255) / 256, 256, 0, stream>>>(batch, gstart, N, G);
  k_cvt<<<(VOC * D + 255) / 256, 256, 0, stream>>>(table, tableb, VOC * D);
  k_cvt_w<<<(4 * 65536 + 255) / 256, 256, 0, stream>>>(root1, W1, wb);
  k_cvt_w<<<(4 * 65536 + 255) / 256, 256, 0, stream>>>(root2, W2, wb + 4 * 65536);

  const int gagg = (RN + 3) / 4;
  const int ggemm = (N + 63) / 64;

  // ---- layer 1 ----
  k_agg<<<gagg, 256, 0, stream>>>(tableb, x, es, off, P0, RN);
  k_lgemm<<<ggemm, 256, 0, stream>>>(tableb, x, P0, wb, b1, P0, N, N);
  // ---- layer 2 ----
  k_agg<<<gagg, 256, 0, stream>>>(P0, nullptr, es, off, P1, RN);
  k_lgemm<<<ggemm, 256, 0, stream>>>(P0, nullptr, P1, wb + 4 * 65536, b2, P1, N, N);

  // ---- pool + head ----
  k_pool<<<G, 256, 0, stream>>>(P1, gstart, gmean, G);
  k_final<<<(G + 3) / 4, 256, 0, stream>>>(gmean, linW, linb, out, G);
}